// Round 7
// baseline (89.583 us; speedup 1.0000x reference)
//
#include <hip/hip_runtime.h>
#include <hip/hip_fp16.h>
#include <math.h>

#define EH   65536
#define LAMF 5.0f
#define SVF  0.36787944117144233f   // exp(-0.2*5) = exp(-1)

typedef __bf16 bf16x8 __attribute__((ext_vector_type(8)));
typedef float  f32x4  __attribute__((ext_vector_type(4)));
typedef _Float16 f16x2 __attribute__((ext_vector_type(2)));

__device__ __forceinline__ float sigmoidf_(float x) { return 1.0f / (1.0f + expf(-x)); }

__device__ __forceinline__ void cvt1(float v, ushort& h, ushort& l) {
    __bf16 bh = (__bf16)v;
    h = __builtin_bit_cast(ushort, bh);
    __bf16 bl = (__bf16)(v - (float)bh);
    l = __builtin_bit_cast(ushort, bl);
}

__device__ __forceinline__ f16x2 u2h(uint u) { return __builtin_bit_cast(f16x2, u); }
__device__ __forceinline__ float2 h2f2u(uint u) {
    __half2 h = __builtin_bit_cast(__half2, u);
    return __half22float2(h);
}

// ============ unified MFMA GEMM, split-bf16, reg-prefetch ===================
// MODE 0: encoder partial  P[z] = x @ W_enc(k-slice, z=0..7)  grid(8,8,8)  64-row
// MODE 1: C45|C23 fused    [h@Wnbr | h@Wself | h@W1a | h@W1b] grid(20,8)   64-row
// MODE 2: agg + epilogue   outm = relu(ew@Hn + Hs + b_mp)     grid(8,16)   32-row
#define LSTR 40   // LDS row stride in ushorts (80B: 16B-aligned rows)
template<int MODE>
__global__ __launch_bounds__(256) void gemm64(
    const float* __restrict__ Aa, const float* __restrict__ Ab,
    const float* __restrict__ B0, const float* __restrict__ B1,
    const float* __restrict__ B2,
    const float* __restrict__ HsC45, const float* __restrict__ bmp,
    float* __restrict__ C0, float* __restrict__ C1)
{
    constexpr int MT = (MODE == 2) ? 1 : 2;          // 16-row frags per wave
    __shared__ ushort As_hi[64*LSTR], As_lo[64*LSTR], Bs_hi[64*LSTR], Bs_lo[64*LSTR];
    const int tid = threadIdx.x;
    const int row0 = blockIdx.y * (MT * 32);

    const float* Ap = Aa; int lda, arow0 = row0, ak = 0;
    const float* Bp; int ldb, kb = 0, bcol0;
    float* Cp; int ldc, ccol0;
    int KS;

    if (MODE == 0) {
        KS = 256; lda = 2048; ak = blockIdx.z * 256;
        Bp = B0; ldb = 512; kb = blockIdx.z * 256; bcol0 = blockIdx.x * 64;
        Cp = C0 + blockIdx.z * 262144; ldc = 512; ccol0 = bcol0;
    } else if (MODE == 1) {
        KS = 512; lda = 512;
        int cb = blockIdx.x;
        if (cb < 8)       { Bp=B0; ldb=512; kb=0;   bcol0=cb*64;        Cp=C0; ldc=1024; ccol0=cb*64; }
        else if (cb < 16) { Bp=B1; ldb=512; kb=0;   bcol0=(cb-8)*64;    Cp=C0; ldc=1024; ccol0=512+(cb-8)*64; }
        else if (cb < 18) { Bp=B2; ldb=128; kb=0;   bcol0=(cb-16)*64;   Cp=C1; ldc=256;  ccol0=(cb-16)*64; }
        else              { Bp=B2; ldb=128; kb=512; bcol0=(cb-18)*64;   Cp=C1; ldc=256;  ccol0=128+(cb-18)*64; }
    } else {
        KS = 256; lda = 256;
        if (row0 < 256) { Ap = Aa; arow0 = row0;       kb = 256; }
        else            { Ap = Ab; arow0 = row0 - 256; kb = 0; }
        Bp = B0; ldb = 1024; bcol0 = blockIdx.x * 64;
        Cp = C0; ldc = 512; ccol0 = bcol0;
    }

    // A-stage map: MT=2 -> 8 floats/thread; MT=1 -> 4 floats/thread
    const int arow = (MT == 2) ? (tid >> 2) : (tid >> 3);
    const int kq   = (MT == 2) ? ((tid & 3) * 8) : ((tid & 7) * 4);
    const int kr = (tid & 15) * 2, nc0 = (tid >> 4) * 4;    // B-stage map (transpose)
    const float* aptr = Ap + (size_t)(arow0 + arow) * lda + ak + kq;
    const float* bptr = Bp + (size_t)(kb + kr) * ldb + bcol0 + nc0;

    f32x4 acc[MT][2] = {};
    const int lane = tid & 63, w = tid >> 6;
    const int qr = (w >> 1) * (MT * 16), qc = (w & 1) * 32;
    const int fr = lane & 15, kg = (lane >> 4) * 8;

    float4 pa0, pa1, pb0, pb1;
    pa0 = *(const float4*)aptr;
    if (MT == 2) pa1 = *(const float4*)(aptr + 4);
    pb0 = *(const float4*)bptr; pb1 = *(const float4*)(bptr + ldb);

    for (int k0 = 0; k0 < KS; k0 += 32) {
        // ---- store staged tile (cvt fp32 -> hi/lo bf16)
        {
            ushort4 h0, l0;
            cvt1(pa0.x,h0.x,l0.x); cvt1(pa0.y,h0.y,l0.y); cvt1(pa0.z,h0.z,l0.z); cvt1(pa0.w,h0.w,l0.w);
            *(ushort4*)&As_hi[arow*LSTR + kq] = h0;
            *(ushort4*)&As_lo[arow*LSTR + kq] = l0;
            if (MT == 2) {
                ushort4 h1, l1;
                cvt1(pa1.x,h1.x,l1.x); cvt1(pa1.y,h1.y,l1.y); cvt1(pa1.z,h1.z,l1.z); cvt1(pa1.w,h1.w,l1.w);
                *(ushort4*)&As_hi[arow*LSTR + kq + 4] = h1;
                *(ushort4*)&As_lo[arow*LSTR + kq + 4] = l1;
            }
            float b0a[4] = {pb0.x, pb0.y, pb0.z, pb0.w};
            float b1a[4] = {pb1.x, pb1.y, pb1.z, pb1.w};
            #pragma unroll
            for (int j = 0; j < 4; ++j) {
                ushort ha, la, hb, lb;
                cvt1(b0a[j], ha, la); cvt1(b1a[j], hb, lb);
                *(uint*)&Bs_hi[(nc0+j)*LSTR + kr] = (uint)ha | ((uint)hb << 16);
                *(uint*)&Bs_lo[(nc0+j)*LSTR + kr] = (uint)la | ((uint)lb << 16);
            }
        }
        __syncthreads();
        if (k0 + 32 < KS) {   // prefetch next tile (overlaps MFMA + barrier)
            pa0 = *(const float4*)(aptr + k0 + 32);
            if (MT == 2) pa1 = *(const float4*)(aptr + k0 + 36);
            const float* bp2 = bptr + (size_t)(k0 + 32) * ldb;
            pb0 = *(const float4*)bp2; pb1 = *(const float4*)(bp2 + ldb);
        }
        bf16x8 ah[MT], al[MT], bh[2], bl[2];
        #pragma unroll
        for (int m = 0; m < MT; ++m) {
            int r = (qr + m*16 + fr) * LSTR + kg;
            ah[m] = *(const bf16x8*)&As_hi[r];
            al[m] = *(const bf16x8*)&As_lo[r];
        }
        #pragma unroll
        for (int n = 0; n < 2; ++n) {
            int r = (qc + n*16 + fr) * LSTR + kg;
            bh[n] = *(const bf16x8*)&Bs_hi[r];
            bl[n] = *(const bf16x8*)&Bs_lo[r];
        }
        #pragma unroll
        for (int m = 0; m < MT; ++m)
            #pragma unroll
            for (int n = 0; n < 2; ++n) {
                acc[m][n] = __builtin_amdgcn_mfma_f32_16x16x32_bf16(ah[m], bh[n], acc[m][n], 0, 0, 0);
                acc[m][n] = __builtin_amdgcn_mfma_f32_16x16x32_bf16(ah[m], bl[n], acc[m][n], 0, 0, 0);
                acc[m][n] = __builtin_amdgcn_mfma_f32_16x16x32_bf16(al[m], bh[n], acc[m][n], 0, 0, 0);
            }
        __syncthreads();
    }

    const int rbase = (lane >> 4) * 4;
    #pragma unroll
    for (int m = 0; m < MT; ++m)
        #pragma unroll
        for (int n = 0; n < 2; ++n)
            #pragma unroll
            for (int r = 0; r < 4; ++r) {
                int gr = row0 + qr + m*16 + rbase + r;
                int gc = ccol0 + qc + n*16 + (lane & 15);
                float v = acc[m][n][r];
                if (MODE == 2) {
                    v += HsC45[(size_t)gr * 1024 + 512 + gc] + bmp[gc];
                    v = fmaxf(v, 0.f);
                }
                Cp[(size_t)gr * ldc + gc] = v;
            }
}

// ============ encoder split-K reduce: h = relu(sum_z P[z] + bias) ===========
__global__ __launch_bounds__(256) void enc_reduce(const float* __restrict__ P,
    const float* __restrict__ bias, float* __restrict__ h)
{
    int e = (blockIdx.x * 256 + threadIdx.x) * 4;
    int col = e & 511;
    float4 s = *(const float4*)&P[e];
    #pragma unroll
    for (int z = 1; z < 8; ++z) {
        float4 v = *(const float4*)&P[e + z * 262144];
        s.x += v.x; s.y += v.y; s.z += v.z; s.w += v.w;
    }
    float4 b = *(const float4*)&bias[col];
    float4 o;
    o.x = fmaxf(s.x + b.x, 0.f);
    o.y = fmaxf(s.y + b.y, 0.f);
    o.z = fmaxf(s.z + b.z, 0.f);
    o.w = fmaxf(s.w + b.w, 0.f);
    *(float4*)&h[e] = o;
}

// ============ per-edge ew + iou (geo MLP inlined, b128 LDS reads) ===========
__global__ __launch_bounds__(256) void edge_geo_kernel(
    const float* __restrict__ C23, const float* __restrict__ coords,
    const float* __restrict__ geo_W1, const float* __restrict__ geo_b1,
    const float* __restrict__ app_b1, const float* __restrict__ app_w2,
    const float* __restrict__ app_b2, const float* __restrict__ geo_w2,
    const float* __restrict__ geo_b2, const float* __restrict__ aff_w,
    const float* __restrict__ aff_b, const float* __restrict__ co,
    const float* __restrict__ gt, float* __restrict__ outp,
    float* __restrict__ ewT0, float* __restrict__ ew2, float* __restrict__ iou1)
{
    __shared__ __align__(16) float sA[16][132], sB[16][132];
    __shared__ __align__(16) float sGA[16][68], sGB[16][68];
    __shared__ __align__(16) float sw2[128], sgw2[64];
    __shared__ float sgw[8][64], sgb[64], scs[16][4], scd[16][4];
    const int tid = threadIdx.x;
    const int half = blockIdx.z;
    const int t0 = blockIdx.y * 16, d0 = blockIdx.x * 16;
    const int sbase = half ? (256 + d0) : t0;   // source-node rows
    const int dbase = half ? t0 : (256 + d0);   // dest-node rows

    // fold gt-copy + scalar consts into half=1 blocks (independent early work)
    if (half == 1) {
        int bid = blockIdx.y * 16 + blockIdx.x;     // 0..255
        if (tid < 64) {
            int o = bid * 256 + tid * 4;
            *(float4*)&outp[EH + o] = *(const float4*)&gt[o];
        }
        if (bid == 0 && tid == 64) {
            outp[2 * EH]     = 256.0f;
            outp[2 * EH + 1] = 256.0f;
        }
    }

    for (int i = tid; i < 16 * 32; i += 256) {
        int rr = i >> 5, c4 = (i & 31) << 2;
        float4 va = *(const float4*)&C23[(sbase + rr) * 256 + c4];
        sA[rr][c4] = va.x; sA[rr][c4+1] = va.y; sA[rr][c4+2] = va.z; sA[rr][c4+3] = va.w;
        float4 vb = *(const float4*)&C23[(dbase + rr) * 256 + 128 + c4];
        float4 b1 = *(const float4*)&app_b1[c4];
        sB[rr][c4] = vb.x + b1.x; sB[rr][c4+1] = vb.y + b1.y;
        sB[rr][c4+2] = vb.z + b1.z; sB[rr][c4+3] = vb.w + b1.w;
    }
    for (int i = tid; i < 512; i += 256) sgw[i >> 6][i & 63] = geo_W1[i];
    if (tid < 64) sgb[tid] = geo_b1[tid];
    else if (tid < 192) sw2[tid - 64] = app_w2[tid - 64];
    else sgw2[tid - 192] = geo_w2[tid - 192];
    if (tid < 64) scs[tid >> 2][tid & 3] = coords[(sbase + (tid >> 2)) * 4 + (tid & 3)];
    else if (tid < 128) { int i = tid - 64; scd[i >> 2][i & 3] = coords[(dbase + (i >> 2)) * 4 + (i & 3)]; }
    __syncthreads();
    for (int v = tid; v < 2048; v += 256) {
        int hh = v >> 10, rr = (v >> 6) & 15, j = v & 63;
        if (hh == 0) {
            sGA[rr][j] = scs[rr][0]*sgw[0][j] + scs[rr][1]*sgw[1][j]
                       + scs[rr][2]*sgw[2][j] + scs[rr][3]*sgw[3][j] + sgb[j];
        } else {
            sGB[rr][j] = scd[rr][0]*sgw[4][j] + scd[rr][1]*sgw[5][j]
                       + scd[rr][2]*sgw[6][j] + scd[rr][3]*sgw[7][j];
        }
    }
    __syncthreads();
    const int tx = tid & 15, ty = tid >> 4;
    const int si = half ? tx : ty;
    const int di = half ? ty : tx;
    float acc1 = 0.f;
    #pragma unroll
    for (int j4 = 0; j4 < 128; j4 += 4) {
        float4 a = *(const float4*)&sA[si][j4];
        float4 b = *(const float4*)&sB[di][j4];
        float4 wv = *(const float4*)&sw2[j4];
        acc1 += fmaxf(a.x + b.x, 0.f) * wv.x + fmaxf(a.y + b.y, 0.f) * wv.y
              + fmaxf(a.z + b.z, 0.f) * wv.z + fmaxf(a.w + b.w, 0.f) * wv.w;
    }
    float x1 = sigmoidf_(acc1 + app_b2[0]);
    float acc2 = 0.f;
    #pragma unroll
    for (int j4 = 0; j4 < 64; j4 += 4) {
        float4 a = *(const float4*)&sGA[si][j4];
        float4 b = *(const float4*)&sGB[di][j4];
        float4 wv = *(const float4*)&sgw2[j4];
        acc2 += fmaxf(a.x + b.x, 0.f) * wv.x + fmaxf(a.y + b.y, 0.f) * wv.y
              + fmaxf(a.z + b.z, 0.f) * wv.z + fmaxf(a.w + b.w, 0.f) * wv.w;
    }
    float x2 = sigmoidf_(acc2 + geo_b2[0]);
    float e = sigmoidf_(x1 * aff_w[0] + x2 * aff_w[1] + aff_b[0]);
    const int t = t0 + ty, d = d0 + tx;
    if (half) ew2[t * 256 + d] = e;
    else      ewT0[d * 256 + t] = e;
    if (half == 0) {
        float4 a = *(const float4*)&co[t * 4];
        float4 b = *(const float4*)&co[(256 + d) * 4];
        float ltx = fmaxf(a.x, b.x), lty = fmaxf(a.y, b.y);
        float rbx = fminf(a.z, b.z), rby = fminf(a.w, b.w);
        float w  = fmaxf(rbx - ltx, 0.f), hh = fmaxf(rby - lty, 0.f);
        float inter = w * hh;
        float areaA = (a.z - a.x) * (a.w - a.y);
        float areaB = (b.z - b.x) * (b.w - b.y);
        iou1[t * 256 + d] = inter / (areaA + areaB - inter + 1e-6f);
    }
}

// ============ gram 32x32 + in-kernel norms + fin/exp epilogue ===============
__global__ __launch_bounds__(256) void gram32(const float* __restrict__ outm,
    const float* __restrict__ iou, const float* __restrict__ finw,
    const float* __restrict__ finb, __half* __restrict__ Mh)
{
    __shared__ ushort As_hi[32*LSTR], As_lo[32*LSTR], Bs_hi[32*LSTR], Bs_lo[32*LSTR];
    __shared__ float snA[32], snB[32];
    const int tid = threadIdx.x;
    const int t0 = blockIdx.y * 32, d0 = blockIdx.x * 32;
    const float* Asrc = outm;
    const float* Bsrc = outm + (size_t)256 * 512;

    const int arow = tid >> 3, kq = (tid & 7) * 4;
    const float* aptr = Asrc + (size_t)(t0 + arow) * 512 + kq;
    const float* bptr = Bsrc + (size_t)(d0 + arow) * 512 + kq;

    f32x4 acc = {};
    float ssA = 0.f, ssB = 0.f;
    const int lane = tid & 63, w = tid >> 6;
    const int qr = (w >> 1) * 16, qc = (w & 1) * 16;
    const int fr = lane & 15, kg = (lane >> 4) * 8;

    float4 pa = *(const float4*)aptr;
    float4 pb = *(const float4*)bptr;

    for (int k0 = 0; k0 < 512; k0 += 32) {
        ssA += pa.x*pa.x + pa.y*pa.y + pa.z*pa.z + pa.w*pa.w;
        ssB += pb.x*pb.x + pb.y*pb.y + pb.z*pb.z + pb.w*pb.w;
        {
            ushort4 h4, l4;
            cvt1(pa.x,h4.x,l4.x); cvt1(pa.y,h4.y,l4.y); cvt1(pa.z,h4.z,l4.z); cvt1(pa.w,h4.w,l4.w);
            *(ushort4*)&As_hi[arow*LSTR + kq] = h4;
            *(ushort4*)&As_lo[arow*LSTR + kq] = l4;
            cvt1(pb.x,h4.x,l4.x); cvt1(pb.y,h4.y,l4.y); cvt1(pb.z,h4.z,l4.z); cvt1(pb.w,h4.w,l4.w);
            *(ushort4*)&Bs_hi[arow*LSTR + kq] = h4;
            *(ushort4*)&Bs_lo[arow*LSTR + kq] = l4;
        }
        __syncthreads();
        if (k0 + 32 < 512) {
            pa = *(const float4*)(aptr + k0 + 32);
            pb = *(const float4*)(bptr + k0 + 32);
        }
        bf16x8 ah, al, bh, bl;
        {
            int r = (qr + fr) * LSTR + kg;
            ah = *(const bf16x8*)&As_hi[r]; al = *(const bf16x8*)&As_lo[r];
        }
        {
            int r = (qc + fr) * LSTR + kg;
            bh = *(const bf16x8*)&Bs_hi[r]; bl = *(const bf16x8*)&Bs_lo[r];
        }
        acc = __builtin_amdgcn_mfma_f32_16x16x32_bf16(ah, bh, acc, 0, 0, 0);
        acc = __builtin_amdgcn_mfma_f32_16x16x32_bf16(ah, bl, acc, 0, 0, 0);
        acc = __builtin_amdgcn_mfma_f32_16x16x32_bf16(al, bh, acc, 0, 0, 0);
        __syncthreads();
    }
    // reduce sumsq across the 8 threads sharing a row (consecutive lanes)
    ssA += __shfl_xor(ssA, 1); ssA += __shfl_xor(ssA, 2); ssA += __shfl_xor(ssA, 4);
    ssB += __shfl_xor(ssB, 1); ssB += __shfl_xor(ssB, 2); ssB += __shfl_xor(ssB, 4);
    if ((tid & 7) == 0) { snA[arow] = ssA; snB[arow] = ssB; }
    __syncthreads();
    const float fw0 = finw[0], fw1 = finw[1], fb = finb[0];
    const int rbase = (lane >> 4) * 4, lc = qc + (lane & 15);
    #pragma unroll
    for (int r = 0; r < 4; ++r) {
        int lr = qr + rbase + r;
        float na = fmaxf(sqrtf(snA[lr]), 1e-6f);
        float nb = fmaxf(sqrtf(snB[lc]), 1e-6f);
        int t = t0 + lr, d = d0 + lc;
        float cosv = acc[r] / (na * nb);
        float fin = sigmoidf_(cosv * fw0 + iou[t * 256 + d] * fw1 + fb);
        Mh[t * 256 + d] = __float2half(expf(fin * LAMF));
    }
}

// ============ Sinkhorn5: 512 thr, M reg-resident both views, fused final ====
// row-view: thread (row=tid>>1, hf=tid&1) holds M[row][128*hf..+128) = 16 uint4
// col-view: thread (cg=tid>>4, s16=tid&15) holds row-pairs {2*s16+32p,+1} p=0..7
//           x cols [8cg..+8), PRE-PACKED as (even,odd) half2 per col = 64 uints
__global__ __launch_bounds__(512, 2) void sinkhorn5(const __half* __restrict__ Mh,
    float* __restrict__ out)
{
    __shared__ float r_f[256], c_f[256], red[8];
    __shared__ __half r_h[256], c_h[256];
    const int tid = threadIdx.x;
    const int row = tid >> 1, hf = tid & 1;
    const int cg = tid >> 4, s16 = tid & 15;

    const uint4* gm = (const uint4*)Mh;            // [256 rows][32 uint4]
    uint4 mr[16];                                  // row-view
    #pragma unroll
    for (int j = 0; j < 16; ++j) mr[j] = gm[row * 32 + hf * 16 + j];
    uint mc[64];                                   // col-view packed pairs
    #pragma unroll
    for (int p = 0; p < 8; ++p) {
        int rA = 2 * s16 + 32 * p;
        uint4 aa = gm[rA * 32 + cg];               // even row, 8 cols
        uint4 bb = gm[(rA + 1) * 32 + cg];         // odd row
        mc[p*8+0] = __builtin_amdgcn_perm(bb.x, aa.x, 0x05040100);
        mc[p*8+1] = __builtin_amdgcn_perm(bb.x, aa.x, 0x07060302);
        mc[p*8+2] = __builtin_amdgcn_perm(bb.y, aa.y, 0x05040100);
        mc[p*8+3] = __builtin_amdgcn_perm(bb.y, aa.y, 0x07060302);
        mc[p*8+4] = __builtin_amdgcn_perm(bb.z, aa.z, 0x05040100);
        mc[p*8+5] = __builtin_amdgcn_perm(bb.z, aa.z, 0x07060302);
        mc[p*8+6] = __builtin_amdgcn_perm(bb.w, aa.w, 0x05040100);
        mc[p*8+7] = __builtin_amdgcn_perm(bb.w, aa.w, 0x07060302);
    }
    if (tid < 256) { c_f[tid] = 1.0f; c_h[tid] = __float2half(1.0f); }
    if (tid == 0) red[1] = 1.0f / SVF;             // makes c256 = 1 at it=0
    __syncthreads();

    const int s8 = s16 & 8, s4 = s16 & 4, s2 = s16 & 2;
    const int mycol = cg * 8 + (s8 ? 4 : 0) + (s4 ? 2 : 0) + (s2 ? 1 : 0);

    for (int it = 0; it < 8; ++it) {
        // ======== ROW phase: r[t] = 1/(sum_d M[t][d] c[d] + SVF*c256)
        float c256 = 1.0f / (SVF * red[1]);
        float a0 = 0.f, a1 = 0.f, a2 = 0.f, a3 = 0.f;
        #pragma unroll
        for (int j = 0; j < 16; ++j) {
            uint4 cu = *(const uint4*)&c_h[hf * 128 + j * 8];
            a0 = __builtin_amdgcn_fdot2(u2h(mr[j].x), u2h(cu.x), a0, false);
            a1 = __builtin_amdgcn_fdot2(u2h(mr[j].y), u2h(cu.y), a1, false);
            a2 = __builtin_amdgcn_fdot2(u2h(mr[j].z), u2h(cu.z), a2, false);
            a3 = __builtin_amdgcn_fdot2(u2h(mr[j].w), u2h(cu.w), a3, false);
        }
        float acc = (a0 + a1) + (a2 + a3);
        acc += __shfl_xor(acc, 1);
        if (tid < 64) {      // Sc = sum c + c256
            float s = c_f[tid] + c_f[tid + 64] + c_f[tid + 128] + c_f[tid + 192];
            #pragma unroll
            for (int o = 32; o; o >>= 1) s += __shfl_down(s, o);
            if (tid == 0) red[0] = s + c256;
        }
        if (hf == 0) {
            float v = 1.0f / (acc + SVF * c256);
            r_f[row] = v; r_h[row] = __float2half(v);
        }
        __syncthreads();

        // ======== COL phase: c[d] = 1/(sum_t M[t][d] r[t] + SVF*r256)
        float r256 = 1.0f / (SVF * red[0]);
        float b0=0.f,b1=0.f,b2=0.f,b3=0.f,b4=0.f,b5=0.f,b6=0.f,b7=0.f;
        #pragma unroll
        for (int p = 0; p < 8; ++p) {
            f16x2 rp = u2h(*(const uint*)&r_h[2 * s16 + 32 * p]);
            b0 = __builtin_amdgcn_fdot2(u2h(mc[p*8+0]), rp, b0, false);
            b1 = __builtin_amdgcn_fdot2(u2h(mc[p*8+1]), rp, b1, false);
            b2 = __builtin_amdgcn_fdot2(u2h(mc[p*8+2]), rp, b2, false);
            b3 = __builtin_amdgcn_fdot2(u2h(mc[p*8+3]), rp, b3, false);
            b4 = __builtin_amdgcn_fdot2(u2h(mc[p*8+4]), rp, b4, false);
            b5 = __builtin_amdgcn_fdot2(u2h(mc[p*8+5]), rp, b5, false);
            b6 = __builtin_amdgcn_fdot2(u2h(mc[p*8+6]), rp, b6, false);
            b7 = __builtin_amdgcn_fdot2(u2h(mc[p*8+7]), rp, b7, false);
        }
        // reduce-scatter over 16 s16-threads -> 1 col/thread (x2 redundancy)
        float t0 = s8 ? b0 : b4, t1 = s8 ? b1 : b5, t2 = s8 ? b2 : b6, t3 = s8 ? b3 : b7;
        t0 = __shfl_xor(t0, 8); t1 = __shfl_xor(t1, 8);
        t2 = __shfl_xor(t2, 8); t3 = __shfl_xor(t3, 8);
        float k0 = (s8 ? b4 : b0) + t0;
        float k1 = (s8 ? b5 : b1) + t1;
        float k2 = (s8 ? b6 : b2) + t2;
        float k3 = (s8 ? b7 : b3) + t3;
        float u0 = s4 ? k0 : k2, u1 = s4 ? k1 : k3;
        u0 = __shfl_xor(u0, 4); u1 = __shfl_xor(u1, 4);
        float m0 = (s4 ? k2 : k0) + u0;
        float m1 = (s4 ? k3 : k1) + u1;
        float w0 = s2 ? m0 : m1;
        w0 = __shfl_xor(w0, 2);
        float s = (s2 ? m1 : m0) + w0;
        s += __shfl_xor(s, 1);
        if (tid < 64) {      // Sr = sum r + r256
            float s2v = r_f[tid] + r_f[tid + 64] + r_f[tid + 128] + r_f[tid + 192];
            #pragma unroll
            for (int o = 32; o; o >>= 1) s2v += __shfl_down(s2v, o);
            if (tid == 0) red[1] = s2v + r256;
        }
        if ((s16 & 1) == 0) {
            float v = 1.0f / (s + SVF * r256);
            c_f[mycol] = v; c_h[mycol] = __float2half(v);
        }
        __syncthreads();
    }

    // ======== fused final: out[row][d] = M0[row][d] * r[row] * c[d]
    float rv = r_f[row];
    #pragma unroll
    for (int j = 0; j < 16; ++j) {
        int cb = hf * 128 + j * 8;
        float4 ca = *(const float4*)&c_f[cb];
        float4 cbv = *(const float4*)&c_f[cb + 4];
        float2 f0 = h2f2u(mr[j].x), f1 = h2f2u(mr[j].y);
        float2 f2 = h2f2u(mr[j].z), f3 = h2f2u(mr[j].w);
        float4 o0, o1;
        o0.x = f0.x * rv * ca.x;  o0.y = f0.y * rv * ca.y;
        o0.z = f1.x * rv * ca.z;  o0.w = f1.y * rv * ca.w;
        o1.x = f2.x * rv * cbv.x; o1.y = f2.y * rv * cbv.y;
        o1.z = f3.x * rv * cbv.z; o1.w = f3.y * rv * cbv.w;
        *(float4*)&out[row * 256 + cb]     = o0;
        *(float4*)&out[row * 256 + cb + 4] = o1;
    }
}

extern "C" void kernel_launch(void* const* d_in, const int* in_sizes, int n_in,
                              void* d_out, int out_size, void* d_ws, size_t ws_size,
                              hipStream_t stream)
{
    const float* x       = (const float*)d_in[0];
    const float* coords  = (const float*)d_in[1];
    const float* co      = (const float*)d_in[2];
    const float* gt      = (const float*)d_in[3];
    const float* W_enc   = (const float*)d_in[5];
    const float* b_enc   = (const float*)d_in[6];
    const float* app_W1  = (const float*)d_in[7];
    const float* app_b1  = (const float*)d_in[8];
    const float* app_w2  = (const float*)d_in[9];
    const float* app_b2  = (const float*)d_in[10];
    const float* geo_W1  = (const float*)d_in[11];
    const float* geo_b1  = (const float*)d_in[12];
    const float* geo_w2  = (const float*)d_in[13];
    const float* geo_b2  = (const float*)d_in[14];
    const float* aff_w   = (const float*)d_in[15];
    const float* aff_b   = (const float*)d_in[16];
    const float* W_self  = (const float*)d_in[17];
    const float* W_nbr   = (const float*)d_in[18];
    const float* b_mp    = (const float*)d_in[19];
    const float* fin_w   = (const float*)d_in[20];
    const float* fin_b   = (const float*)d_in[21];
    float* out = (float*)d_out;

    // ---- workspace layout (stream-order-safe aliasing)
    char* W = (char*)d_ws;
    float*  P     = (float*)(W + 0);         // [8][512][512] (dead after reduce)
    float*  h     = (float*)(W + 8388608);   // [512][512]
    float*  C45   = (float*)(W + 0);         // [512][1024] (Hn | Hs)  aliases P
    float*  C23   = (float*)(W + 2097152);   // [512][256]  (Aapp | Bapp)
    float*  ewT0  = (float*)(W + 2621440);   // [256 d][256 t]
    float*  ew2   = (float*)(W + 2883584);   // [256 t][256 d]
    float*  iou1  = (float*)(W + 3145728);   // [256][256]
    __half* Mh    = (__half*)(W + 3407872);  // [256][256] fp16
    float*  outm  = (float*)(W + 3670016);   // [512][512]

    // 1) encoder partials: P[z] = x @ W_enc[z-slice], z=0..7
    gemm64<0><<<dim3(8, 8, 8), 256, 0, stream>>>(x, nullptr, W_enc, nullptr, nullptr,
        nullptr, nullptr, P, nullptr);
    // 2) h = relu(sum_z P + b_enc)
    enc_reduce<<<256, 256, 0, stream>>>(P, b_enc, h);
    // 3) C45 = h@[Wnbr|Wself], C23 = h@[W1a|W1b]   (one fused launch)
    gemm64<1><<<dim3(20, 8), 256, 0, stream>>>(h, nullptr, W_nbr, W_self, app_W1,
        nullptr, nullptr, C45, C23);
    // 4) per-edge ew + iou (geo MLP inlined) + gt copy + consts
    edge_geo_kernel<<<dim3(16, 16, 2), 256, 0, stream>>>(C23, coords, geo_W1, geo_b1,
        app_b1, app_w2, app_b2, geo_w2, geo_b2, aff_w, aff_b, co, gt, out,
        ewT0, ew2, iou1);
    // 5) outm = relu(ew@Hn + Hs + b_mp)   (32-row tiles, 128 blocks)
    gemm64<2><<<dim3(8, 16), 256, 0, stream>>>(ew2, ewT0, C45, nullptr, nullptr,
        C45, b_mp, outm, nullptr);
    // 6) gram + norms + fin + M0(fp16)
    gram32<<<dim3(8, 8), 256, 0, stream>>>(outm, iou1, fin_w, fin_b, Mh);
    // 7) Sinkhorn + fused final output (register-resident M)
    sinkhorn5<<<1, 512, 0, stream>>>(Mh, out);
}